// Round 11
// baseline (4331.417 us; speedup 1.0000x reference)
//
#include <hip/hip_runtime.h>

#define TT 512
#define FF 16
#define HH 256
#define OUTLEN 64
#define NT 9          // K tiles of 32 -> K=288 (h 0..255, bias 256, x/inp 257..272, pad)
#define PITCH 296     // uH/uL row pitch in halfs
#define ROWS 16       // batch rows per block -> 256 blocks, 1 per CU
#define NBLK (4096/ROWS)
#define NFRAG (NT*16*4*64)   // half8 fragments per phase = 36864 (589824 B)
// R11 = R10 (8 waves x 2 slots, A-read dedup, 2688us) + kt0,1 JOIN THE
//       PINNED TIER (LDS B-tier eliminated).
//   R10 post-mortem: all gates hit (VGPR 128, no spill, MfmaUtil 47.7).
//   Step = 11.9K cyc: MFMA 5.7K (= hi/lo floor), LDS ~4.3K, VALU ~4.5K.
//   At 2 waves/SIMD the arch budget is 256; pinning kt0,1 (+64 regs) kills
//   the 128 B-tier ds_read_b128/step (~1.6K cyc LDS) and the 128KB Bt
//   buffer. This is R8's idea executed in the regime where it fits
//   (R8 spilled at the 128-reg/4-wave budget; here budget is 256/2-wave).
// B residency (2 tiers), per wave-slot pair:
//   kt0..4  -> loop-carried-pinned (160 regs = 5 kt x 2 slots x 4 frags)
//   kt5..8  -> streamed 256 KB/step/CU, single-set rotation, each refill
//              16-32 MFMAs (310-620+ cyc) before consumption:
//              kt5 -> rf kt6 -> [pin0] -> kt6 -> rf kt7 -> [pin1] -> kt7 ->
//              rf kt8 -> [pin2,pin3] -> kt8 -> rf NEXT kt5 -> [pin4]
// LDS: uH/uL 18.5 KB + red 1 KB = 19.5 KB (Bt gone).
// GATES: VGPR ~220-256, WRITE ~5.6MB (no spill), MfmaUtil 52-58.

typedef _Float16 half8 __attribute__((ext_vector_type(8)));
typedef float f32x4 __attribute__((ext_vector_type(4)));

// 1-ulp rcp instead of the ~10-instr exact-division sequence (no fast-math here)
__device__ __forceinline__ float fsig(float x) {
  return __builtin_amdgcn_rcpf(1.0f + __expf(-x));
}
__device__ __forceinline__ float ftanh(float x) { return 2.0f * fsig(x + x) - 1.0f; }

// frag half8 idx = ((kt*16 + w)*4 + g)*64 + lane
//   col = g*256 + w*16 + (lane&15);  k = kt*32 + (lane>>4)*8 + j
__global__ void prep_kernel(const float* __restrict__ eWih, const float* __restrict__ eWhh,
                            const float* __restrict__ eb,  const float* __restrict__ dWih,
                            const float* __restrict__ dWhh, const float* __restrict__ db,
                            _Float16* __restrict__ E, _Float16* __restrict__ D) {
  int idx = blockIdx.x * 256 + threadIdx.x;
  if (idx >= NFRAG * 8) return;
  int j    = idx & 7;
  int lane = (idx >> 3) & 63;
  int rest = idx >> 9;         // (kt*16 + w)*4 + g
  int g    = rest & 3;
  int wv   = (rest >> 2) & 15;
  int kt   = rest >> 6;
  int col  = g * 256 + wv * 16 + (lane & 15);
  int k    = kt * 32 + (lane >> 4) * 8 + j;
  float ve = 0.f, vd = 0.f;
  if (k < HH)        { ve = eWhh[col * HH + k]; vd = dWhh[col * HH + k]; }
  else if (k == HH)  { ve = eb[col];            vd = db[col]; }
  else if (k <= 272) { ve = eWih[col * FF + (k - 257)]; if (k == 257) vd = dWih[col]; }
  E[idx] = (_Float16)ve;
  D[idx] = (_Float16)vd;
}

// strm points at kt5 base for wave-slot 2w. bf[s][g] = frag of slot 2w+s.
__device__ __forceinline__ void refill_bf(half8 (&bf)[2][4], const half8* __restrict__ rp) {
#pragma unroll
  for (int s = 0; s < 2; ++s)
#pragma unroll
    for (int g = 0; g < 4; ++g) bf[s][g] = rp[s * 256 + g * 64];
}

// pp points at kt0 base for slot 2w. Load kt0..4 for both slots.
__device__ __forceinline__ void fill_pk(half8 (&pk)[5][2][4], const half8* __restrict__ pp) {
#pragma unroll
  for (int i = 0; i < 5; ++i)
#pragma unroll
    for (int s = 0; s < 2; ++s)
#pragma unroll
      for (int g = 0; g < 4; ++g) pk[i][s][g] = pp[i * 4096 + s * 256 + g * 64];
}

// Loop-carried register pin (R4's proven mechanism: FETCH 8.9GB -> 131MB).
#define PIN_PK(pk)                                                   \
  _Pragma("unroll")                                                  \
  for (int _i = 0; _i < 5; ++_i)                                     \
    _Pragma("unroll")                                                \
    for (int _s = 0; _s < 2; ++_s)                                   \
      _Pragma("unroll")                                              \
      for (int _g = 0; _g < 4; ++_g)                                 \
        asm volatile("" : "+v"(pk[_i][_s][_g]));

// One A-read pair (AH,AL) feeds BOTH column-slots: 32 MFMAs per kt per wave.
__device__ __forceinline__ void consume_bf(const _Float16* __restrict__ uHp,
                                           const _Float16* __restrict__ uLp,
                                           const int kt, const half8 (&bf)[2][4],
                                           f32x4 (&acc)[2][4]) {
  half8 AH = *(const half8*)(uHp + kt * 32);
  half8 AL = *(const half8*)(uLp + kt * 32);
#pragma unroll
  for (int s = 0; s < 2; ++s) {
#pragma unroll
    for (int g = 0; g < 4; ++g) acc[s][g] = __builtin_amdgcn_mfma_f32_16x16x32_f16(AH, bf[s][g], acc[s][g], 0, 0, 0);
#pragma unroll
    for (int g = 0; g < 4; ++g) acc[s][g] = __builtin_amdgcn_mfma_f32_16x16x32_f16(AL, bf[s][g], acc[s][g], 0, 0, 0);
  }
}

__device__ __forceinline__ void consume_pin(const _Float16* __restrict__ uHp,
                                            const _Float16* __restrict__ uLp,
                                            const int kt, const half8 (&pk)[5][2][4],
                                            f32x4 (&acc)[2][4]) {
  half8 AH = *(const half8*)(uHp + kt * 32);
  half8 AL = *(const half8*)(uLp + kt * 32);
#pragma unroll
  for (int s = 0; s < 2; ++s) {
#pragma unroll
    for (int g = 0; g < 4; ++g) acc[s][g] = __builtin_amdgcn_mfma_f32_16x16x32_f16(AH, pk[kt][s][g], acc[s][g], 0, 0, 0);
#pragma unroll
    for (int g = 0; g < 4; ++g) acc[s][g] = __builtin_amdgcn_mfma_f32_16x16x32_f16(AL, pk[kt][s][g], acc[s][g], 0, 0, 0);
  }
}

// One step's matvec for this wave's 128 gate columns (both slots).
// Stream rotation interleaved with the 5 pinned tiles for refill lead time.
__device__ __forceinline__ void mfma_step(const _Float16* __restrict__ uHp,
                                          const _Float16* __restrict__ uLp,
                                          const half8* __restrict__ strm,
                                          const half8 (&pk)[5][2][4],
                                          half8 (&bf)[2][4],
                                          f32x4 (&acc)[2][4]) {
#pragma unroll
  for (int s = 0; s < 2; ++s)
#pragma unroll
    for (int g = 0; g < 4; ++g) acc[s][g] = (f32x4){0.f, 0.f, 0.f, 0.f};

  consume_bf(uHp, uLp, 5, bf, acc);  refill_bf(bf, strm + 1 * 4096);  // -> kt6
  consume_pin(uHp, uLp, 0, pk, acc);                                  // 32-MFMA lead
  consume_bf(uHp, uLp, 6, bf, acc);  refill_bf(bf, strm + 2 * 4096);  // -> kt7
  consume_pin(uHp, uLp, 1, pk, acc);
  consume_bf(uHp, uLp, 7, bf, acc);  refill_bf(bf, strm + 3 * 4096);  // -> kt8
  consume_pin(uHp, uLp, 2, pk, acc);
  consume_pin(uHp, uLp, 3, pk, acc);                                  // 64-MFMA lead
  consume_bf(uHp, uLp, 8, bf, acc);  refill_bf(bf, strm);             // -> NEXT kt5
  consume_pin(uHp, uLp, 4, pk, acc); // + cell update covers next-kt5 drain
}

// 256 blocks x 512 threads (8 waves, 2/SIMD). Block owns 16 batch rows and all
// 1024 gate columns. Wave w owns slots 2w,2w+1 -> units (2w+s)*16 + l15.
__global__ __launch_bounds__(512, 2) void seq2seq_kernel(
    const float* __restrict__ x,
    const _Float16* __restrict__ E, const _Float16* __restrict__ Dw,
    const float* __restrict__ Wout, const float* __restrict__ bout,
    float* __restrict__ out) {
  __shared__ _Float16 uH[ROWS * PITCH];  // 9.25 KB activation hi [m][k]
  __shared__ _Float16 uL[ROWS * PITCH];  // 9.25 KB activation lo
  __shared__ float red[ROWS * 16];       // 1 KB   head partials [row][slot]
  // 19.5 KB total (B weight tiers live in registers + L2 stream now)

  const int tid  = threadIdx.x;
  const int w    = tid >> 6;             // 0..7
  const int lane = tid & 63;
  const int quad = lane >> 4;
  const int l15  = lane & 15;
  const int b0   = blockIdx.x * ROWS;

  const half8* E8 = (const half8*)E;
  const half8* D8 = (const half8*)Dw;

  for (int i = tid; i < ROWS * PITCH; i += 512) { uH[i] = (_Float16)0.f; uL[i] = (_Float16)0.f; }
  __syncthreads();
  if (tid < ROWS) uH[tid * PITCH + 256] = (_Float16)1.0f; // bias-one column

  const _Float16* uHp = uH + l15 * PITCH + quad * 8;
  const _Float16* uLp = uL + l15 * PITCH + quad * 8;
  const half8* strm = E8 + 5 * 4096 + (2 * w) * 256 + lane;  // kt5 base

  float cc[2][4] = {{0.f, 0.f, 0.f, 0.f}, {0.f, 0.f, 0.f, 0.f}};
  float wou[2];
  wou[0] = Wout[(2 * w) * 16 + l15];
  wou[1] = Wout[(2 * w + 1) * 16 + l15];
  const float bo  = bout[0];
  const int   xr  = (tid >> 4) * PITCH + 257 + (tid & 15);
  const float* xp = x + ((long)(b0 + (tid >> 4)) * TT) * FF + (tid & 15);

  half8 pk[5][2][4];
  fill_pk(pk, E8 + (2 * w) * 256 + lane);  // pin kt0..4 (encoder)
  half8 bf[2][4];
  refill_bf(bf, strm);                   // prologue: kt5 in flight

  // ---------------- encoder: 512 steps ----------------
  float xv = (tid < 256) ? xp[0] : 0.f;
#pragma unroll 1
  for (int t = 0; t < TT; ++t) {
    PIN_PK(pk);                          // loop-carried pin: kt0..4 stay resident
    if (tid < 256) {                     // stage x(t): 16 rows x 16 features, hi/lo
      _Float16 hs = (_Float16)xv;
      uH[xr] = hs; uL[xr] = (_Float16)(xv - (float)hs);
      if (t + 1 < TT) xv = xp[(t + 1) * FF];
    }
    __syncthreads();                     // h(t-1) + x(t) visible

    f32x4 acc[2][4];
    mfma_step(uHp, uLp, strm, pk, bf, acc);
    __syncthreads();                     // all A reads done before h overwrite

#pragma unroll
    for (int s = 0; s < 2; ++s) {
      const int unit = (2 * w + s) * 16 + l15;
#pragma unroll
      for (int rg = 0; rg < 4; ++rg) {
        float ig = fsig(acc[s][0][rg]);
        float fg = fsig(acc[s][1][rg]);
        float gg = ftanh(acc[s][2][rg]);
        float og = fsig(acc[s][3][rg]);
        cc[s][rg] = fg * cc[s][rg] + ig * gg;
        float hv = og * ftanh(cc[s][rg]);
        const int m = quad * 4 + rg;
        _Float16 hs = (_Float16)hv;
        uH[m * PITCH + unit] = hs;
        uL[m * PITCH + unit] = (_Float16)(hv - (float)hs);
      }
    }
  }

  // ---- phase swap: decoder pinned regs + stream base ----
  __syncthreads();
  strm = D8 + 5 * 4096 + (2 * w) * 256 + lane;
  fill_pk(pk, D8 + (2 * w) * 256 + lane);  // re-pin kt0..4 (decoder)
  refill_bf(bf, strm);                   // overwrite stale encoder kt5
  if (tid < ROWS) { uH[tid * PITCH + 257] = (_Float16)0.f; uL[tid * PITCH + 257] = (_Float16)0.f; }
  // stale x cols 258..272: decoder weight rows there are zero -> no contribution

  // ---------------- decoder: 64 autoregressive steps ----------------
#pragma unroll 1
  for (int td = 0; td < OUTLEN; ++td) {
    PIN_PK(pk);                          // loop-carried pin (decoder weights)
    __syncthreads();                     // h + inp visible

    f32x4 acc[2][4];
    mfma_step(uHp, uLp, strm, pk, bf, acc);
    __syncthreads();                     // reads done before overwrite

    float p[2][4];
#pragma unroll
    for (int s = 0; s < 2; ++s) {
      const int unit = (2 * w + s) * 16 + l15;
#pragma unroll
      for (int rg = 0; rg < 4; ++rg) {
        float ig = fsig(acc[s][0][rg]);
        float fg = fsig(acc[s][1][rg]);
        float gg = ftanh(acc[s][2][rg]);
        float og = fsig(acc[s][3][rg]);
        cc[s][rg] = fg * cc[s][rg] + ig * gg;
        float hv = og * ftanh(cc[s][rg]);
        const int m = quad * 4 + rg;
        _Float16 hs = (_Float16)hv;
        uH[m * PITCH + unit] = hs;
        uL[m * PITCH + unit] = (_Float16)(hv - (float)hs);
        p[s][rg] = hv * wou[s];
      }
    }
    // head: sum each slot's 16 units (16-lane groups share rows)
#pragma unroll
    for (int off = 1; off < 16; off <<= 1)
#pragma unroll
      for (int s = 0; s < 2; ++s)
#pragma unroll
        for (int rg = 0; rg < 4; ++rg) p[s][rg] += __shfl_xor(p[s][rg], off, 64);
    if (l15 == 0) {
#pragma unroll
      for (int s = 0; s < 2; ++s)
#pragma unroll
        for (int rg = 0; rg < 4; ++rg) red[(quad * 4 + rg) * 16 + 2 * w + s] = p[s][rg];
    }
    __syncthreads();
    if (tid < ROWS) {                    // sum 16 slots -> out + autoregressive feedback
      float s = bo;
#pragma unroll
      for (int u = 0; u < 16; ++u) s += red[tid * 16 + u];
      out[(long)(b0 + tid) * OUTLEN + td] = s;
      _Float16 hs = (_Float16)s;
      uH[tid * PITCH + 257] = hs;
      uL[tid * PITCH + 257] = (_Float16)(s - (float)hs);
    }
  }
}

extern "C" void kernel_launch(void* const* d_in, const int* in_sizes, int n_in,
                              void* d_out, int out_size, void* d_ws, size_t ws_size,
                              hipStream_t stream) {
  const float* x    = (const float*)d_in[0];
  const float* eWih = (const float*)d_in[1];
  const float* eWhh = (const float*)d_in[2];
  const float* eb   = (const float*)d_in[3];
  const float* dWih = (const float*)d_in[4];
  const float* dWhh = (const float*)d_in[5];
  const float* db   = (const float*)d_in[6];
  const float* Wout = (const float*)d_in[7];
  const float* bout = (const float*)d_in[8];
  float* out = (float*)d_out;

  _Float16* E  = (_Float16*)d_ws;        // 589824 B
  _Float16* Dw = E + NFRAG * 8;          // 589824 B

  prep_kernel<<<dim3((NFRAG * 8 + 255) / 256), dim3(256), 0, stream>>>(
      eWih, eWhh, eb, dWih, dWhh, db, E, Dw);
  seq2seq_kernel<<<dim3(NBLK), dim3(512), 0, stream>>>(
      x, E, Dw, Wout, bout, out);
}